// Round 1
// baseline (8799.271 us; speedup 1.0000x reference)
//
#include <hip/hip_runtime.h>

// FeedBack LSTM: 128 warmup steps + 31 AR steps, B=4096, UNITS=512, FEAT=12.
// Strategy:
//  - AR feedback folded into weights: z = h@(U + Wd@W) + (b + bd@W)  (exact),
//    so every step is the same [4096,512]@[512,2048] bf16 MFMA GEMM.
//  - warmup x_t@W handled as one extra MFMA k-step (K padded 12->32), with
//    A-fragments loaded directly from global x (no LDS staging).
//  - 128x128 z-tile (128 rows x [32 units x 4 gates]), BK=64, 4 waves,
//    2-phase double-buffered LDS via global_load_lds(16B). Gate columns are
//    interleaved (gate = ln&3) so i/f/g/o of one unit sit in 4 adjacent lanes
//    -> epilogue combines gates with 3 __shfl_xor, writes h (bf16) + c (f32).
//  - h ping-pongs between 2 buffers (same-kernel read/write race), c in-place.

typedef __bf16 bf16;
typedef __attribute__((ext_vector_type(8))) __bf16 bf16x8;
typedef __attribute__((ext_vector_type(4))) float f32x4;

#define AS1 __attribute__((address_space(1)))
#define AS3 __attribute__((address_space(3)))

#define NB    4096
#define TSEQ  128
#define FEAT  12
#define UNITS 512
#define NZ    2048   // 4*UNITS
#define OUTS  32

#define BM 128
#define BK 64

// workspace layout (bytes)
#define OFF_UT   ((size_t)0)
#define OFF_UTA  (OFF_UT  + (size_t)NZ*UNITS*2)   // Ut:  [2048][512] bf16 (U^T)
#define OFF_WT   (OFF_UTA + (size_t)NZ*UNITS*2)   // Uta: [2048][512] bf16 ((U+Wd@W)^T)
#define OFF_B2   (OFF_WT  + (size_t)NZ*32*2)      // Wt:  [2048][32] bf16 (W^T, k-padded)
#define OFF_H0   (OFF_B2  + (size_t)NZ*4)         // b2:  [2048] f32 (b + bd@W)
#define OFF_H1   (OFF_H0  + (size_t)NB*UNITS*2)   // h ping
#define OFF_C    (OFF_H1  + (size_t)NB*UNITS*2)   // h pong
#define WS_NEED  (OFF_C   + (size_t)NB*UNITS*4)   // c f32

__device__ __forceinline__ float sigm_(float x){ return 1.f/(1.f + __expf(-x)); }
__device__ __forceinline__ float tanh_(float x){
  float a = fabsf(x), e = __expf(-2.f*a), t = (1.f-e)/(1.f+e);
  return x < 0.f ? -t : t;
}
__device__ __forceinline__ void gld16(const void* g, void* l){
  __builtin_amdgcn_global_load_lds((const AS1 void*)g, (AS3 void*)l, 16, 0, 0);
}

// ---------------- prep: U^T and (U + Wd@W)^T in bf16 --------------------
__global__ void prep_u_kernel(const float* __restrict__ U, const float* __restrict__ W,
                              const float* __restrict__ Wd,
                              bf16* __restrict__ Ut, bf16* __restrict__ Uta){
  __shared__ float su[64][65];
  __shared__ float sa[64][65];
  const int n0 = blockIdx.x * 64;          // 32 blocks over N=2048
  const int k0 = blockIdx.y * 64;          // 8 blocks over K=512
  const int tx = threadIdx.x & 63;
  const int rr = threadIdx.x >> 6;         // 0..3
  #pragma unroll 4
  for (int it = 0; it < 16; ++it){
    int k = it*4 + rr;
    float u = U[(size_t)(k0+k)*NZ + n0 + tx];
    float a = u;
    #pragma unroll
    for (int j = 0; j < FEAT; ++j) a += Wd[(k0+k)*FEAT + j] * W[(size_t)j*NZ + n0 + tx];
    su[tx][k] = u;   // transpose in LDS (+1 pad)
    sa[tx][k] = a;
  }
  __syncthreads();
  #pragma unroll 4
  for (int it = 0; it < 16; ++it){
    int nl = it*4 + rr;
    Ut [(size_t)(n0+nl)*UNITS + k0 + tx] = (bf16)su[nl][tx];
    Uta[(size_t)(n0+nl)*UNITS + k0 + tx] = (bf16)sa[nl][tx];
  }
}

// ---------------- prep: W^T (k-padded to 32) and b2 = b + bd@W ----------
__global__ void prep_w_kernel(const float* __restrict__ W, const float* __restrict__ b,
                              const float* __restrict__ bd,
                              bf16* __restrict__ Wt, float* __restrict__ b2){
  const int n = blockIdx.x*256 + threadIdx.x;   // 8 blocks
  float acc = b[n];
  #pragma unroll
  for (int j = 0; j < FEAT; ++j){
    float w = W[(size_t)j*NZ + n];
    Wt[(size_t)n*32 + j] = (bf16)w;
    acc += bd[j] * w;
  }
  #pragma unroll
  for (int j = FEAT; j < 32; ++j) Wt[(size_t)n*32 + j] = (bf16)0.f;
  b2[n] = acc;
}

// ---------------- one LSTM step (fused GEMM + gates) --------------------
// grid 512 = 32 m-tiles x 16 unit-tiles, 256 threads (4 waves).
template<int HAS_X>
__launch_bounds__(256, 2)
__global__ void lstm_step_kernel(const bf16* __restrict__ hin, bf16* __restrict__ hout,
                                 float* __restrict__ c,
                                 const bf16* __restrict__ Bt,    // [2048][512] (N-major)
                                 const float* __restrict__ bias, // [2048]
                                 const float* __restrict__ xt,   // x + t*FEAT, row stride TSEQ*FEAT
                                 const bf16* __restrict__ Wt)    // [2048][32]
{
  __shared__ alignas(16) bf16 Abuf[2][BM*BK];
  __shared__ alignas(16) bf16 Bbuf[2][BM*BK];

  // XCD-aware swizzle: 512 blocks -> 8 chunks of 64 (4 m-tiles x all 16 nu)
  int bid = blockIdx.x;
  bid = (bid & 7) * 64 + (bid >> 3);
  const int mt = bid >> 4;
  const int nu = bid & 15;
  const int m0 = mt * BM;

  const int tid  = threadIdx.x;
  const int lane = tid & 63;
  const int wid  = tid >> 6;        // 0..3
  const int wm   = wid >> 1, wn = wid & 1;
  const int l15  = lane & 15;
  const int kgrp = lane >> 4;       // 0..3
  const int l7   = lane & 7;
  const int l8   = lane >> 3;       // 0..7

  f32x4 acc[4][4];
  #pragma unroll
  for (int i = 0; i < 4; ++i)
    #pragma unroll
    for (int j = 0; j < 4; ++j) acc[i][j] = f32x4{0.f,0.f,0.f,0.f};

  auto stage = [&](int bi, int k0){
    #pragma unroll
    for (int i = 0; i < 4; ++i){                       // A: h rows
      int row = wid*32 + i*8;                          // wave-uniform base row
      const bf16* src = hin + (size_t)(m0 + row + l8)*UNITS + k0 + l7*8;
      gld16(src, &Abuf[bi][row*BK]);
    }
    #pragma unroll
    for (int i = 0; i < 4; ++i){                       // B: interleaved gate cols
      int ln  = wid*32 + i*8;                          // wave-uniform base
      int lnl = ln + l8;
      int zc  = (lnl & 3)*UNITS + nu*32 + (lnl >> 2);  // gate=ln&3, unit=ln>>2
      const bf16* src = Bt + (size_t)zc*UNITS + k0 + l7*8;
      gld16(src, &Bbuf[bi][ln*BK]);
    }
  };

  auto compute = [&](int bi){
    #pragma unroll
    for (int kk = 0; kk < 2; ++kk){
      bf16x8 af[4], bq[4];
      #pragma unroll
      for (int f = 0; f < 4; ++f){
        af[f] = *reinterpret_cast<const bf16x8*>(&Abuf[bi][(wm*64 + f*16 + l15)*BK + (kk*4 + kgrp)*8]);
        bq[f] = *reinterpret_cast<const bf16x8*>(&Bbuf[bi][(wn*64 + f*16 + l15)*BK + (kk*4 + kgrp)*8]);
      }
      #pragma unroll
      for (int i = 0; i < 4; ++i)
        #pragma unroll
        for (int j = 0; j < 4; ++j)
          acc[i][j] = __builtin_amdgcn_mfma_f32_16x16x32_bf16(af[i], bq[j], acc[i][j], 0, 0, 0);
    }
  };

  stage(0, 0);
  __syncthreads();
  int cur = 0;
  #pragma unroll 1
  for (int it = 0; it < UNITS/BK; ++it){
    if (it < UNITS/BK - 1) stage(cur ^ 1, (it+1)*BK);
    compute(cur);
    __syncthreads();
    cur ^= 1;
  }

  if (HAS_X){
    // extra k-step: x_t (K=12 padded to 32), A from global, B from Wt
    bf16x8 xa[4], wq[4];
    #pragma unroll
    for (int f = 0; f < 4; ++f){
      int row = m0 + wm*64 + f*16 + l15;
      const float* xr = xt + (size_t)row * (TSEQ*FEAT);
      bf16x8 v;
      #pragma unroll
      for (int j = 0; j < 8; ++j){
        int k = kgrp*8 + j;
        v[j] = (k < FEAT) ? (bf16)xr[k] : (bf16)0.f;
      }
      xa[f] = v;
      int lnl = wn*64 + f*16 + l15;
      int zc  = (lnl & 3)*UNITS + nu*32 + (lnl >> 2);
      wq[f] = *reinterpret_cast<const bf16x8*>(Wt + (size_t)zc*32 + kgrp*8);
    }
    #pragma unroll
    for (int i = 0; i < 4; ++i)
      #pragma unroll
      for (int j = 0; j < 4; ++j)
        acc[i][j] = __builtin_amdgcn_mfma_f32_16x16x32_bf16(xa[i], wq[j], acc[i][j], 0, 0, 0);
  }

  // epilogue: gate = lane&3; 4 adjacent lanes hold i,f,g,o of same (row,unit)
  const int gid = lane & 3;
  float bv[4];
  #pragma unroll
  for (int f = 0; f < 4; ++f){
    int lnl = wn*64 + f*16 + l15;
    bv[f] = bias[(lnl & 3)*UNITS + nu*32 + (lnl >> 2)];
  }
  #pragma unroll
  for (int fm = 0; fm < 4; ++fm){
    #pragma unroll
    for (int fn = 0; fn < 4; ++fn){
      int lnl  = wn*64 + fn*16 + l15;
      int unit = nu*32 + (lnl >> 2);
      #pragma unroll
      for (int j = 0; j < 4; ++j){
        float v  = acc[fm][fn][j] + bv[fn];
        float t0 = (gid == 2) ? tanh_(v) : sigm_(v);   // i,f,o: sigmoid; g: tanh
        float g1 = __shfl_xor(t0, 1);
        float g2 = __shfl_xor(t0, 2);
        float g3 = __shfl_xor(g1, 2);
        if (gid == 0){                                  // t0=i, g1=f, g2=g, g3=o
          int row = m0 + wm*64 + fm*16 + kgrp*4 + j;
          size_t idx = (size_t)row*UNITS + unit;
          float cold = c[idx];
          float cnew = g1*cold + t0*g2;
          float hnew = g3*tanh_(cnew);
          c[idx]    = cnew;
          hout[idx] = (bf16)hnew;
        }
      }
    }
  }
}

// ---------------- pred = h @ Wd + bd -> out[:, s, :] --------------------
__global__ void pred_kernel(const bf16* __restrict__ h, const float* __restrict__ Wd,
                            const float* __restrict__ bd, float* __restrict__ out, int s){
  __shared__ float wds[UNITS*FEAT];
  const int tid = threadIdx.x;
  for (int i = tid; i < UNITS*FEAT; i += 256) wds[i] = Wd[i];
  __syncthreads();
  const int lane = tid & 63, wid = tid >> 6;
  const int row  = blockIdx.x*4 + wid;
  bf16x8 hv = *reinterpret_cast<const bf16x8*>(h + (size_t)row*UNITS + lane*8);
  float hf[8];
  #pragma unroll
  for (int i = 0; i < 8; ++i) hf[i] = (float)hv[i];
  float res = 0.f;
  #pragma unroll
  for (int j = 0; j < FEAT; ++j){
    float p = 0.f;
    #pragma unroll
    for (int i = 0; i < 8; ++i) p += hf[i]*wds[(lane*8 + i)*FEAT + j];
    #pragma unroll
    for (int m = 1; m < 64; m <<= 1) p += __shfl_xor(p, m);
    if (lane == j) res = p + bd[j];
  }
  if (lane < FEAT) out[(size_t)row*(OUTS*FEAT) + s*FEAT + lane] = res;
}

// ------------------------------------------------------------------------
extern "C" void kernel_launch(void* const* d_in, const int* in_sizes, int n_in,
                              void* d_out, int out_size, void* d_ws, size_t ws_size,
                              hipStream_t stream){
  const float* x  = (const float*)d_in[0];
  const float* W  = (const float*)d_in[1];
  const float* U  = (const float*)d_in[2];
  const float* b  = (const float*)d_in[3];
  const float* Wd = (const float*)d_in[4];
  const float* bd = (const float*)d_in[5];
  float* out = (float*)d_out;
  (void)in_sizes; (void)n_in; (void)out_size;
  if (ws_size < WS_NEED) return;   // fail visibly rather than corrupt memory

  char* ws  = (char*)d_ws;
  bf16* Ut  = (bf16*)(ws + OFF_UT);
  bf16* Uta = (bf16*)(ws + OFF_UTA);
  bf16* Wt  = (bf16*)(ws + OFF_WT);
  float* b2 = (float*)(ws + OFF_B2);
  bf16* h0  = (bf16*)(ws + OFF_H0);
  bf16* h1  = (bf16*)(ws + OFF_H1);
  float* c  = (float*)(ws + OFF_C);

  hipMemsetAsync(h0, 0, (size_t)NB*UNITS*2, stream);
  hipMemsetAsync(c,  0, (size_t)NB*UNITS*4, stream);
  prep_u_kernel<<<dim3(32, 8), 256, 0, stream>>>(U, W, Wd, Ut, Uta);
  prep_w_kernel<<<8, 256, 0, stream>>>(W, b, bd, Wt, b2);

  bf16* hcur = h0; bf16* hnxt = h1;
  for (int t = 0; t < TSEQ; ++t){
    lstm_step_kernel<1><<<512, 256, 0, stream>>>(hcur, hnxt, c, Ut, b, x + t*FEAT, Wt);
    bf16* tmp = hcur; hcur = hnxt; hnxt = tmp;
  }
  pred_kernel<<<NB/4, 256, 0, stream>>>(hcur, Wd, bd, out, 0);
  for (int s = 1; s < OUTS; ++s){
    lstm_step_kernel<0><<<512, 256, 0, stream>>>(hcur, hnxt, c, Uta, b2, nullptr, nullptr);
    bf16* tmp = hcur; hcur = hnxt; hnxt = tmp;
    pred_kernel<<<NB/4, 256, 0, stream>>>(hcur, Wd, bd, out, s);
  }
}

// Round 2
// 4297.593 us; speedup vs baseline: 2.0475x; 2.0475x over previous
//
#include <hip/hip_runtime.h>

// FeedBack LSTM: 128 warmup + 31 AR steps, B=4096, UNITS=512, FEAT=12.
//  - AR feedback folded into weights: z = h@(U + Wd@W) + (b + bd@W) (exact).
//  - Per step: [4096,512]@[512,2048] bf16 MFMA GEMM fused with gate math.
//  - R2: reg-staged 2-deep prefetch pipeline (loads issued 2 K-iters ahead,
//    ds_write 1 iter ahead, raw s_barrier + lgkmcnt(0) only -> no vmcnt(0)
//    drain), XOR-swizzled LDS tiles (conflict-free b128), z-through-LDS
//    epilogue (all-lane transcendentals, coalesced c/h RMW).

typedef __bf16 bf16;
typedef __attribute__((ext_vector_type(8))) __bf16 bf16x8;
typedef __attribute__((ext_vector_type(4))) float f32x4;

#define NB    4096
#define TSEQ  128
#define FEAT  12
#define UNITS 512
#define NZ    2048
#define OUTS  32

#define BM 128
#define BK 64

// workspace layout (bytes)
#define OFF_UT   ((size_t)0)
#define OFF_UTA  (OFF_UT  + (size_t)NZ*UNITS*2)
#define OFF_WT   (OFF_UTA + (size_t)NZ*UNITS*2)
#define OFF_B2   (OFF_WT  + (size_t)NZ*32*2)
#define OFF_H0   (OFF_B2  + (size_t)NZ*4)
#define OFF_H1   (OFF_H0  + (size_t)NB*UNITS*2)
#define OFF_C    (OFF_H1  + (size_t)NB*UNITS*2)
#define WS_NEED  (OFF_C   + (size_t)NB*UNITS*4)

__device__ __forceinline__ float fast_exp2(float x){ return __builtin_amdgcn_exp2f(x); }
__device__ __forceinline__ float fast_rcp (float x){ return __builtin_amdgcn_rcpf(x); }
__device__ __forceinline__ float sigm_(float x){ return fast_rcp(1.f + fast_exp2(-1.4426950408889634f*x)); }
__device__ __forceinline__ float tanh_(float x){ return 1.f - 2.f*fast_rcp(1.f + fast_exp2(2.8853900817779268f*x)); }

// ---------------- prep: U^T and (U + Wd@W)^T in bf16 --------------------
__global__ void prep_u_kernel(const float* __restrict__ U, const float* __restrict__ W,
                              const float* __restrict__ Wd,
                              bf16* __restrict__ Ut, bf16* __restrict__ Uta){
  __shared__ float su[64][65];
  __shared__ float sa[64][65];
  const int n0 = blockIdx.x * 64;
  const int k0 = blockIdx.y * 64;
  const int tx = threadIdx.x & 63;
  const int rr = threadIdx.x >> 6;
  #pragma unroll 4
  for (int it = 0; it < 16; ++it){
    int k = it*4 + rr;
    float u = U[(size_t)(k0+k)*NZ + n0 + tx];
    float a = u;
    #pragma unroll
    for (int j = 0; j < FEAT; ++j) a += Wd[(k0+k)*FEAT + j] * W[(size_t)j*NZ + n0 + tx];
    su[tx][k] = u;
    sa[tx][k] = a;
  }
  __syncthreads();
  #pragma unroll 4
  for (int it = 0; it < 16; ++it){
    int nl = it*4 + rr;
    Ut [(size_t)(n0+nl)*UNITS + k0 + tx] = (bf16)su[nl][tx];
    Uta[(size_t)(n0+nl)*UNITS + k0 + tx] = (bf16)sa[nl][tx];
  }
}

// ---------------- prep: W^T (k-padded to 32) and b2 = b + bd@W ----------
__global__ void prep_w_kernel(const float* __restrict__ W, const float* __restrict__ b,
                              const float* __restrict__ bd,
                              bf16* __restrict__ Wt, float* __restrict__ b2){
  const int n = blockIdx.x*256 + threadIdx.x;
  float acc = b[n];
  #pragma unroll
  for (int j = 0; j < FEAT; ++j){
    float w = W[(size_t)j*NZ + n];
    Wt[(size_t)n*32 + j] = (bf16)w;
    acc += bd[j] * w;
  }
  #pragma unroll
  for (int j = FEAT; j < 32; ++j) Wt[(size_t)n*32 + j] = (bf16)0.f;
  b2[n] = acc;
}

// ---------------- one LSTM step (fused GEMM + gates) --------------------
// grid 512 = 32 m-tiles x 16 unit-tiles, 256 threads (4 waves).
template<int HAS_X>
__launch_bounds__(256, 2)
__global__ void lstm_step_kernel(const bf16* __restrict__ hin, bf16* __restrict__ hout,
                                 float* __restrict__ c,
                                 const bf16* __restrict__ Bt,    // [2048][512]
                                 const float* __restrict__ bias, // [2048]
                                 const float* __restrict__ xt,   // x + t*FEAT (f32, row stride 1536)
                                 const bf16* __restrict__ Wt)    // [2048][32]
{
  __shared__ alignas(16) char lds[65536];
  // A0 @0, A1 @16K, B0 @32K, B1 @48K (each 16KB = 128 rows x 128B); z reuses all 64KB.

  int bid = blockIdx.x;
  bid = (bid & 7) * 64 + (bid >> 3);          // XCD swizzle: rows stay XCD-local
  const int mt = bid >> 4;
  const int nu = bid & 15;
  const int m0 = mt * BM;

  const int tid  = threadIdx.x;
  const int lane = tid & 63;
  const int wid  = tid >> 6;
  const int wm   = wid >> 1, wn = wid & 1;
  const int l15  = lane & 15;
  const int kgrp = lane >> 4;
  const int l7   = lane & 7;
  const int l8   = lane >> 3;

  // staging addresses (row = wid*32 + i*8 + l8; 16B slot l7, swizzled slot l7^l8)
  const bf16* agp = hin + (size_t)(m0 + wid*32 + l8)*UNITS + l7*8;
  const int   aoff = (wid*32 + l8)*128 + ((l7 ^ l8) << 4);
  int zcv[4];
  #pragma unroll
  for (int i = 0; i < 4; ++i){
    int lnl = wid*32 + i*8 + l8;
    zcv[i] = ((lnl & 3) << 9) + nu*32 + (lnl >> 2);   // gate-interleaved z column
  }

  f32x4 acc[4][4];
  #pragma unroll
  for (int i = 0; i < 4; ++i)
    #pragma unroll
    for (int j = 0; j < 4; ++j) acc[i][j] = f32x4{0.f,0.f,0.f,0.f};

  bf16x8 rA[2][4], rB[2][4];

  auto load_set = [&](int s, int k0){
    #pragma unroll
    for (int i = 0; i < 4; ++i){
      rA[s][i] = *reinterpret_cast<const bf16x8*>(agp + (size_t)i*8*UNITS + k0);
      rB[s][i] = *reinterpret_cast<const bf16x8*>(Bt + (size_t)zcv[i]*UNITS + k0 + l7*8);
    }
  };
  auto write_set = [&](int s, int bi){
    char* A = lds + (bi << 14);
    char* B = lds + 32768 + (bi << 14);
    #pragma unroll
    for (int i = 0; i < 4; ++i){
      *reinterpret_cast<bf16x8*>(A + aoff + i*1024) = rA[s][i];
      *reinterpret_cast<bf16x8*>(B + aoff + i*1024) = rB[s][i];
    }
  };
  auto compute = [&](int bi){
    const char* A = lds + (bi << 14);
    const char* B = lds + 32768 + (bi << 14);
    #pragma unroll
    for (int kk = 0; kk < 2; ++kk){
      const int sa = (((kk*4 + kgrp) ^ (l15 & 7)) << 4);
      bf16x8 af[4], bq[4];
      #pragma unroll
      for (int f = 0; f < 4; ++f){
        af[f] = *reinterpret_cast<const bf16x8*>(A + (wm*64 + f*16 + l15)*128 + sa);
        bq[f] = *reinterpret_cast<const bf16x8*>(B + (wn*64 + f*16 + l15)*128 + sa);
      }
      #pragma unroll
      for (int i = 0; i < 4; ++i)
        #pragma unroll
        for (int j = 0; j < 4; ++j)
          acc[i][j] = __builtin_amdgcn_mfma_f32_16x16x32_bf16(af[i], bq[j], acc[i][j], 0, 0, 0);
    }
  };

  // hoisted x / Wt fragments (HAS_X) and epilogue biases — latency hidden
  bf16x8 xa[4], wq[4];
  if (HAS_X){
    #pragma unroll
    for (int f = 0; f < 4; ++f){
      int row = m0 + wm*64 + f*16 + l15;
      const float* xr = xt + (size_t)row * (TSEQ*FEAT);
      bf16x8 v;
      #pragma unroll
      for (int j = 0; j < 8; ++j) v[j] = (bf16)0.f;
      if (kgrp == 0){
        float4 a = *reinterpret_cast<const float4*>(xr);
        float4 b = *reinterpret_cast<const float4*>(xr + 4);
        v[0]=(bf16)a.x; v[1]=(bf16)a.y; v[2]=(bf16)a.z; v[3]=(bf16)a.w;
        v[4]=(bf16)b.x; v[5]=(bf16)b.y; v[6]=(bf16)b.z; v[7]=(bf16)b.w;
      } else if (kgrp == 1){
        float4 a = *reinterpret_cast<const float4*>(xr + 8);
        v[0]=(bf16)a.x; v[1]=(bf16)a.y; v[2]=(bf16)a.z; v[3]=(bf16)a.w;
      }
      xa[f] = v;
      int lnl = wn*64 + f*16 + l15;
      int zc  = ((lnl & 3) << 9) + nu*32 + (lnl >> 2);
      wq[f] = *reinterpret_cast<const bf16x8*>(Wt + (size_t)zc*32 + kgrp*8);
    }
  }
  const int eu  = tid & 31;          // epilogue unit 0..31
  const int erg = tid >> 5;          // 0..7 row group (16 rows each)
  const int cu  = nu*32 + eu;
  float bi_ = bias[0*UNITS + cu];
  float bf_ = bias[1*UNITS + cu];
  float bg_ = bias[2*UNITS + cu];
  float bo_ = bias[3*UNITS + cu];

  // ---- pipeline prologue: tiles 0,1 -> regs; tile 0 -> LDS ----
  load_set(0, 0);
  load_set(1, BK);
  write_set(0, 0);                      // compiler emits counted vmcnt(8) here
  asm volatile("s_waitcnt lgkmcnt(0)" ::: "memory");
  __builtin_amdgcn_sched_barrier(0);
  __builtin_amdgcn_s_barrier();

  // ---- main loop: compute tile t, prefetch t+2 to regs, write t+1 to LDS
  #pragma unroll
  for (int t = 0; t < 8; ++t){
    const int p = t & 1;
    if (t + 2 < 8) load_set(p, (t+2)*BK);
    compute(p);
    if (t < 7){
      write_set(p ^ 1, p ^ 1);          // counted vmcnt(8 or 0), no drain of t+2
      asm volatile("s_waitcnt lgkmcnt(0)" ::: "memory");
      __builtin_amdgcn_sched_barrier(0);
      __builtin_amdgcn_s_barrier();
    }
  }

  if (HAS_X){
    #pragma unroll
    for (int i = 0; i < 4; ++i)
      #pragma unroll
      for (int j = 0; j < 4; ++j)
        acc[i][j] = __builtin_amdgcn_mfma_f32_16x16x32_bf16(xa[i], wq[j], acc[i][j], 0, 0, 0);
  }

  // ---- z through LDS: store transposed+swizzled, re-read all-lane ----
  asm volatile("s_waitcnt lgkmcnt(0)" ::: "memory");
  __builtin_amdgcn_sched_barrier(0);
  __builtin_amdgcn_s_barrier();         // everyone done reading A/B tiles

  #pragma unroll
  for (int fm = 0; fm < 4; ++fm){
    #pragma unroll
    for (int fn = 0; fn < 4; ++fn){
      int col  = wn*64 + fn*16 + l15;
      int srow = wm*16 + fm*4 + kgrp;   // 16B slot index (4 rows per slot)
      *reinterpret_cast<f32x4*>(lds + col*512 + ((srow ^ (col & 7)) << 4)) = acc[fm][fn];
    }
  }
  asm volatile("s_waitcnt lgkmcnt(0)" ::: "memory");
  __builtin_amdgcn_sched_barrier(0);
  __builtin_amdgcn_s_barrier();

  // epilogue: each thread owns unit eu, rows erg*16..+15; fully coalesced c/h
  const int rbase = m0 + erg*16;
  float cold[16];
  #pragma unroll
  for (int r = 0; r < 16; ++r) cold[r] = c[(size_t)(rbase + r)*UNITS + cu];

  #pragma unroll
  for (int q = 0; q < 4; ++q){
    const int s = erg*4 + q;
    f32x4 zi = *reinterpret_cast<const f32x4*>(lds + (eu*4+0)*512 + ((s ^ ((eu*4+0)&7)) << 4));
    f32x4 zf = *reinterpret_cast<const f32x4*>(lds + (eu*4+1)*512 + ((s ^ ((eu*4+1)&7)) << 4));
    f32x4 zg = *reinterpret_cast<const f32x4*>(lds + (eu*4+2)*512 + ((s ^ ((eu*4+2)&7)) << 4));
    f32x4 zo = *reinterpret_cast<const f32x4*>(lds + (eu*4+3)*512 + ((s ^ ((eu*4+3)&7)) << 4));
    #pragma unroll
    for (int rr = 0; rr < 4; ++rr){
      int r = q*4 + rr;
      float iv = sigm_(zi[rr] + bi_);
      float fv = sigm_(zf[rr] + bf_);
      float gv = tanh_(zg[rr] + bg_);
      float ov = sigm_(zo[rr] + bo_);
      float cn = fv*cold[r] + iv*gv;
      size_t idx = (size_t)(rbase + r)*UNITS + cu;
      c[idx]    = cn;
      hout[idx] = (bf16)(ov*tanh_(cn));
    }
  }
}

// ---------------- pred = h @ Wd + bd -> out[:, s, :] --------------------
__global__ void pred_kernel(const bf16* __restrict__ h, const float* __restrict__ Wd,
                            const float* __restrict__ bd, float* __restrict__ out, int s){
  __shared__ float wds[UNITS*FEAT];
  const int tid = threadIdx.x;
  for (int i = tid; i < UNITS*FEAT; i += 256) wds[i] = Wd[i];
  __syncthreads();
  const int lane = tid & 63, wid = tid >> 6;
  const int row  = blockIdx.x*4 + wid;
  bf16x8 hv = *reinterpret_cast<const bf16x8*>(h + (size_t)row*UNITS + lane*8);
  float hf[8];
  #pragma unroll
  for (int i = 0; i < 8; ++i) hf[i] = (float)hv[i];
  float res = 0.f;
  #pragma unroll
  for (int j = 0; j < FEAT; ++j){
    float p = 0.f;
    #pragma unroll
    for (int i = 0; i < 8; ++i) p += hf[i]*wds[(lane*8 + i)*FEAT + j];
    #pragma unroll
    for (int m = 1; m < 64; m <<= 1) p += __shfl_xor(p, m);
    if (lane == j) res = p + bd[j];
  }
  if (lane < FEAT) out[(size_t)row*(OUTS*FEAT) + s*FEAT + lane] = res;
}

// ------------------------------------------------------------------------
extern "C" void kernel_launch(void* const* d_in, const int* in_sizes, int n_in,
                              void* d_out, int out_size, void* d_ws, size_t ws_size,
                              hipStream_t stream){
  const float* x  = (const float*)d_in[0];
  const float* W  = (const float*)d_in[1];
  const float* U  = (const float*)d_in[2];
  const float* b  = (const float*)d_in[3];
  const float* Wd = (const float*)d_in[4];
  const float* bd = (const float*)d_in[5];
  float* out = (float*)d_out;
  (void)in_sizes; (void)n_in; (void)out_size;
  if (ws_size < WS_NEED) return;

  char* ws  = (char*)d_ws;
  bf16* Ut  = (bf16*)(ws + OFF_UT);
  bf16* Uta = (bf16*)(ws + OFF_UTA);
  bf16* Wt  = (bf16*)(ws + OFF_WT);
  float* b2 = (float*)(ws + OFF_B2);
  bf16* h0  = (bf16*)(ws + OFF_H0);
  bf16* h1  = (bf16*)(ws + OFF_H1);
  float* c  = (float*)(ws + OFF_C);

  hipMemsetAsync(h0, 0, (size_t)NB*UNITS*2, stream);
  hipMemsetAsync(c,  0, (size_t)NB*UNITS*4, stream);
  prep_u_kernel<<<dim3(32, 8), 256, 0, stream>>>(U, W, Wd, Ut, Uta);
  prep_w_kernel<<<8, 256, 0, stream>>>(W, b, bd, Wt, b2);

  bf16* hcur = h0; bf16* hnxt = h1;
  for (int t = 0; t < TSEQ; ++t){
    lstm_step_kernel<1><<<512, 256, 0, stream>>>(hcur, hnxt, c, Ut, b, x + t*FEAT, Wt);
    bf16* tmp = hcur; hcur = hnxt; hnxt = tmp;
  }
  pred_kernel<<<NB/4, 256, 0, stream>>>(hcur, Wd, bd, out, 0);
  for (int s = 1; s < OUTS; ++s){
    lstm_step_kernel<0><<<512, 256, 0, stream>>>(hcur, hnxt, c, Uta, b2, nullptr, nullptr);
    bf16* tmp = hcur; hcur = hnxt; hnxt = tmp;
    pred_kernel<<<NB/4, 256, 0, stream>>>(hcur, Wd, bd, out, s);
  }
}

// Round 3
// 2949.734 us; speedup vs baseline: 2.9831x; 1.4569x over previous
//
#include <hip/hip_runtime.h>

// FeedBack LSTM: 128 warmup + 31 AR steps, B=4096, UNITS=512, FEAT=12.
//  - AR feedback folded into weights: z = h@(U + Wd@W) + (b + bd@W) (exact).
//  - Per step: [4096,512]@[512,2048] bf16 MFMA GEMM fused with gate math.
//  - R2: reg-staged 2-deep prefetch pipeline, XOR-swizzled LDS, z-through-LDS
//    epilogue.
//  - R3: pred via MFMA (h @ Wd) over the stored h-history (hall ring in ws,
//    one kernel at end; per-step fallback if ws too small); hoisted c-reads.

typedef __bf16 bf16;
typedef __attribute__((ext_vector_type(8))) __bf16 bf16x8;
typedef __attribute__((ext_vector_type(4))) float f32x4;

#define NB    4096
#define TSEQ  128
#define FEAT  12
#define UNITS 512
#define NZ    2048
#define OUTS  32

#define BM 128
#define BK 64

// workspace layout (bytes)
#define OFF_UT   ((size_t)0)
#define OFF_UTA  (OFF_UT  + (size_t)NZ*UNITS*2)    // 2 MB
#define OFF_WT   (OFF_UTA + (size_t)NZ*UNITS*2)    // 2 MB
#define OFF_B2   (OFF_WT  + (size_t)NZ*32*2)       // 128 KB
#define OFF_WDT  (OFF_B2  + (size_t)NZ*4)          // 8 KB
#define OFF_H0   (OFF_WDT + (size_t)16*UNITS*2)    // 16 KB
#define OFF_H1   (OFF_H0  + (size_t)NB*UNITS*2)    // 4 MB
#define OFF_C    (OFF_H1  + (size_t)NB*UNITS*2)    // 4 MB
#define WS_NEED  (OFF_C   + (size_t)NB*UNITS*4)    // +8 MB
#define OFF_HALL (WS_NEED)
#define HALL_SL  ((size_t)NB*UNITS)                // elements per slot
#define WS_BIG   (OFF_HALL + (size_t)OUTS*NB*UNITS*2)   // +128 MB

__device__ __forceinline__ float fast_exp2(float x){ return __builtin_amdgcn_exp2f(x); }
__device__ __forceinline__ float fast_rcp (float x){ return __builtin_amdgcn_rcpf(x); }
__device__ __forceinline__ float sigm_(float x){ return fast_rcp(1.f + fast_exp2(-1.4426950408889634f*x)); }
__device__ __forceinline__ float tanh_(float x){ return 1.f - 2.f*fast_rcp(1.f + fast_exp2(2.8853900817779268f*x)); }

// ---------------- prep: U^T and (U + Wd@W)^T in bf16 --------------------
__global__ void prep_u_kernel(const float* __restrict__ U, const float* __restrict__ W,
                              const float* __restrict__ Wd,
                              bf16* __restrict__ Ut, bf16* __restrict__ Uta){
  __shared__ float su[64][65];
  __shared__ float sa[64][65];
  const int n0 = blockIdx.x * 64;
  const int k0 = blockIdx.y * 64;
  const int tx = threadIdx.x & 63;
  const int rr = threadIdx.x >> 6;
  #pragma unroll 4
  for (int it = 0; it < 16; ++it){
    int k = it*4 + rr;
    float u = U[(size_t)(k0+k)*NZ + n0 + tx];
    float a = u;
    #pragma unroll
    for (int j = 0; j < FEAT; ++j) a += Wd[(k0+k)*FEAT + j] * W[(size_t)j*NZ + n0 + tx];
    su[tx][k] = u;
    sa[tx][k] = a;
  }
  __syncthreads();
  #pragma unroll 4
  for (int it = 0; it < 16; ++it){
    int nl = it*4 + rr;
    Ut [(size_t)(n0+nl)*UNITS + k0 + tx] = (bf16)su[nl][tx];
    Uta[(size_t)(n0+nl)*UNITS + k0 + tx] = (bf16)sa[nl][tx];
  }
}

// ------- prep: W^T (k-padded), b2 = b + bd@W, Wdt = Wd^T (bf16) ---------
__global__ void prep_w_kernel(const float* __restrict__ W, const float* __restrict__ b,
                              const float* __restrict__ bd, const float* __restrict__ Wd,
                              bf16* __restrict__ Wt, float* __restrict__ b2,
                              bf16* __restrict__ Wdt){
  const int n = blockIdx.x*256 + threadIdx.x;
  float acc = b[n];
  #pragma unroll
  for (int j = 0; j < FEAT; ++j){
    float w = W[(size_t)j*NZ + n];
    Wt[(size_t)n*32 + j] = (bf16)w;
    acc += bd[j] * w;
  }
  #pragma unroll
  for (int j = FEAT; j < 32; ++j) Wt[(size_t)n*32 + j] = (bf16)0.f;
  b2[n] = acc;
  if (n < UNITS){
    #pragma unroll
    for (int j = 0; j < FEAT; ++j) Wdt[(size_t)j*UNITS + n] = (bf16)Wd[(size_t)n*FEAT + j];
    #pragma unroll
    for (int j = FEAT; j < 16; ++j) Wdt[(size_t)j*UNITS + n] = (bf16)0.f;
  }
}

// ---------------- one LSTM step (fused GEMM + gates) --------------------
// grid 512 = 32 m-tiles x 16 unit-tiles, 256 threads (4 waves).
template<int HAS_X>
__launch_bounds__(256, 2)
__global__ void lstm_step_kernel(const bf16* __restrict__ hin, bf16* __restrict__ hout,
                                 float* __restrict__ c,
                                 const bf16* __restrict__ Bt,    // [2048][512]
                                 const float* __restrict__ bias, // [2048]
                                 const float* __restrict__ xt,   // x + t*FEAT (f32, row stride 1536)
                                 const bf16* __restrict__ Wt)    // [2048][32]
{
  __shared__ alignas(16) char lds[65536];
  // A0 @0, A1 @16K, B0 @32K, B1 @48K (each 16KB = 128 rows x 128B); z reuses all 64KB.

  int bid = blockIdx.x;
  bid = (bid & 7) * 64 + (bid >> 3);          // XCD swizzle: rows stay XCD-local
  const int mt = bid >> 4;
  const int nu = bid & 15;
  const int m0 = mt * BM;

  const int tid  = threadIdx.x;
  const int lane = tid & 63;
  const int wid  = tid >> 6;
  const int wm   = wid >> 1, wn = wid & 1;
  const int l15  = lane & 15;
  const int kgrp = lane >> 4;
  const int l7   = lane & 7;
  const int l8   = lane >> 3;

  const bf16* agp = hin + (size_t)(m0 + wid*32 + l8)*UNITS + l7*8;
  const int   aoff = (wid*32 + l8)*128 + ((l7 ^ l8) << 4);
  int zcv[4];
  #pragma unroll
  for (int i = 0; i < 4; ++i){
    int lnl = wid*32 + i*8 + l8;
    zcv[i] = ((lnl & 3) << 9) + nu*32 + (lnl >> 2);   // gate-interleaved z column
  }

  f32x4 acc[4][4];
  #pragma unroll
  for (int i = 0; i < 4; ++i)
    #pragma unroll
    for (int j = 0; j < 4; ++j) acc[i][j] = f32x4{0.f,0.f,0.f,0.f};

  bf16x8 rA[2][4], rB[2][4];

  auto load_set = [&](int s, int k0){
    #pragma unroll
    for (int i = 0; i < 4; ++i){
      rA[s][i] = *reinterpret_cast<const bf16x8*>(agp + (size_t)i*8*UNITS + k0);
      rB[s][i] = *reinterpret_cast<const bf16x8*>(Bt + (size_t)zcv[i]*UNITS + k0 + l7*8);
    }
  };
  auto write_set = [&](int s, int bi){
    char* A = lds + (bi << 14);
    char* B = lds + 32768 + (bi << 14);
    #pragma unroll
    for (int i = 0; i < 4; ++i){
      *reinterpret_cast<bf16x8*>(A + aoff + i*1024) = rA[s][i];
      *reinterpret_cast<bf16x8*>(B + aoff + i*1024) = rB[s][i];
    }
  };
  auto compute = [&](int bi){
    const char* A = lds + (bi << 14);
    const char* B = lds + 32768 + (bi << 14);
    #pragma unroll
    for (int kk = 0; kk < 2; ++kk){
      const int sa = (((kk*4 + kgrp) ^ (l15 & 7)) << 4);
      bf16x8 af[4], bq[4];
      #pragma unroll
      for (int f = 0; f < 4; ++f){
        af[f] = *reinterpret_cast<const bf16x8*>(A + (wm*64 + f*16 + l15)*128 + sa);
        bq[f] = *reinterpret_cast<const bf16x8*>(B + (wn*64 + f*16 + l15)*128 + sa);
      }
      #pragma unroll
      for (int i = 0; i < 4; ++i)
        #pragma unroll
        for (int j = 0; j < 4; ++j)
          acc[i][j] = __builtin_amdgcn_mfma_f32_16x16x32_bf16(af[i], bq[j], acc[i][j], 0, 0, 0);
    }
  };

  // hoisted x / Wt fragments (HAS_X) and epilogue biases
  bf16x8 xa[4], wq[4];
  if (HAS_X){
    #pragma unroll
    for (int f = 0; f < 4; ++f){
      int row = m0 + wm*64 + f*16 + l15;
      const float* xr = xt + (size_t)row * (TSEQ*FEAT);
      bf16x8 v;
      #pragma unroll
      for (int j = 0; j < 8; ++j) v[j] = (bf16)0.f;
      if (kgrp == 0){
        float4 a = *reinterpret_cast<const float4*>(xr);
        float4 b = *reinterpret_cast<const float4*>(xr + 4);
        v[0]=(bf16)a.x; v[1]=(bf16)a.y; v[2]=(bf16)a.z; v[3]=(bf16)a.w;
        v[4]=(bf16)b.x; v[5]=(bf16)b.y; v[6]=(bf16)b.z; v[7]=(bf16)b.w;
      } else if (kgrp == 1){
        float4 a = *reinterpret_cast<const float4*>(xr + 8);
        v[0]=(bf16)a.x; v[1]=(bf16)a.y; v[2]=(bf16)a.z; v[3]=(bf16)a.w;
      }
      xa[f] = v;
      int lnl = wn*64 + f*16 + l15;
      int zc  = ((lnl & 3) << 9) + nu*32 + (lnl >> 2);
      wq[f] = *reinterpret_cast<const bf16x8*>(Wt + (size_t)zc*32 + kgrp*8);
    }
  }
  const int eu  = tid & 31;          // epilogue unit 0..31
  const int erg = tid >> 5;          // 0..7 row group (16 rows each)
  const int cu  = nu*32 + eu;
  float bi_ = bias[0*UNITS + cu];
  float bf_ = bias[1*UNITS + cu];
  float bg_ = bias[2*UNITS + cu];
  float bo_ = bias[3*UNITS + cu];

  // ---- pipeline prologue: tiles 0,1 -> regs; tile 0 -> LDS ----
  load_set(0, 0);
  load_set(1, BK);

  // hoisted c-reads: issue now, consumed (counted-vmcnt) in epilogue
  const int rbase = m0 + erg*16;
  float cold[16];
  {
    const float* cp = c + (size_t)rbase*UNITS + cu;
    #pragma unroll
    for (int r = 0; r < 16; ++r) cold[r] = cp[(size_t)r*UNITS];
  }

  write_set(0, 0);                      // counted vmcnt wait on set-0 loads
  asm volatile("s_waitcnt lgkmcnt(0)" ::: "memory");
  __builtin_amdgcn_sched_barrier(0);
  __builtin_amdgcn_s_barrier();

  // ---- main loop: compute tile t, prefetch t+2 to regs, write t+1 to LDS
  #pragma unroll
  for (int t = 0; t < 8; ++t){
    const int p = t & 1;
    if (t + 2 < 8) load_set(p, (t+2)*BK);
    compute(p);
    if (t < 7){
      write_set(p ^ 1, p ^ 1);
      asm volatile("s_waitcnt lgkmcnt(0)" ::: "memory");
      __builtin_amdgcn_sched_barrier(0);
      __builtin_amdgcn_s_barrier();
    }
  }

  if (HAS_X){
    #pragma unroll
    for (int i = 0; i < 4; ++i)
      #pragma unroll
      for (int j = 0; j < 4; ++j)
        acc[i][j] = __builtin_amdgcn_mfma_f32_16x16x32_bf16(xa[i], wq[j], acc[i][j], 0, 0, 0);
  }

  // ---- z through LDS: store transposed+swizzled, re-read all-lane ----
  asm volatile("s_waitcnt lgkmcnt(0)" ::: "memory");
  __builtin_amdgcn_sched_barrier(0);
  __builtin_amdgcn_s_barrier();

  #pragma unroll
  for (int fm = 0; fm < 4; ++fm){
    #pragma unroll
    for (int fn = 0; fn < 4; ++fn){
      int col  = wn*64 + fn*16 + l15;
      int srow = wm*16 + fm*4 + kgrp;
      *reinterpret_cast<f32x4*>(lds + col*512 + ((srow ^ (col & 7)) << 4)) = acc[fm][fn];
    }
  }
  asm volatile("s_waitcnt lgkmcnt(0)" ::: "memory");
  __builtin_amdgcn_sched_barrier(0);
  __builtin_amdgcn_s_barrier();

  #pragma unroll
  for (int q = 0; q < 4; ++q){
    const int s = erg*4 + q;
    f32x4 zi = *reinterpret_cast<const f32x4*>(lds + (eu*4+0)*512 + ((s ^ ((eu*4+0)&7)) << 4));
    f32x4 zf = *reinterpret_cast<const f32x4*>(lds + (eu*4+1)*512 + ((s ^ ((eu*4+1)&7)) << 4));
    f32x4 zg = *reinterpret_cast<const f32x4*>(lds + (eu*4+2)*512 + ((s ^ ((eu*4+2)&7)) << 4));
    f32x4 zo = *reinterpret_cast<const f32x4*>(lds + (eu*4+3)*512 + ((s ^ ((eu*4+3)&7)) << 4));
    #pragma unroll
    for (int rr = 0; rr < 4; ++rr){
      int r = q*4 + rr;
      float iv = sigm_(zi[rr] + bi_);
      float fv = sigm_(zf[rr] + bf_);
      float gv = tanh_(zg[rr] + bg_);
      float ov = sigm_(zo[rr] + bo_);
      float cn = fv*cold[r] + iv*gv;
      size_t idx = (size_t)(rbase + r)*UNITS + cu;
      c[idx]    = cn;
      hout[idx] = (bf16)(ov*tanh_(cn));
    }
  }
}

// ------ pred: out[:, slot, :] = h_slot @ Wd + bd via 16x16x32 MFMA ------
// grid (NB/64, nslots), block 256 (4 waves x 16 rows).
__global__ void pred_all_kernel(const bf16* __restrict__ hbase, size_t slot_stride, int s0,
                                const bf16* __restrict__ Wdt,   // [16][512] bf16
                                const float* __restrict__ bd, float* __restrict__ out){
  const int slot = s0 + blockIdx.y;
  const bf16* h  = hbase + (size_t)blockIdx.y * slot_stride;
  const int tid = threadIdx.x, lane = tid & 63, wid = tid >> 6;
  const int l15 = lane & 15, kg = lane >> 4;
  const int r0 = blockIdx.x*64 + wid*16;
  f32x4 acc = f32x4{0.f,0.f,0.f,0.f};
  const bf16* ap = h   + (size_t)(r0 + l15)*UNITS + kg*8;
  const bf16* bp = Wdt + (size_t)l15*UNITS + kg*8;
  #pragma unroll
  for (int ks = 0; ks < 16; ++ks){
    bf16x8 a = *reinterpret_cast<const bf16x8*>(ap + ks*32);
    bf16x8 b = *reinterpret_cast<const bf16x8*>(bp + ks*32);
    acc = __builtin_amdgcn_mfma_f32_16x16x32_bf16(a, b, acc, 0, 0, 0);
  }
  if (l15 < FEAT){
    float bdv = bd[l15];
    #pragma unroll
    for (int r = 0; r < 4; ++r){
      int row = r0 + kg*4 + r;
      out[(size_t)row*(OUTS*FEAT) + slot*FEAT + l15] = acc[r] + bdv;
    }
  }
}

// ------------------------------------------------------------------------
extern "C" void kernel_launch(void* const* d_in, const int* in_sizes, int n_in,
                              void* d_out, int out_size, void* d_ws, size_t ws_size,
                              hipStream_t stream){
  const float* x  = (const float*)d_in[0];
  const float* W  = (const float*)d_in[1];
  const float* U  = (const float*)d_in[2];
  const float* b  = (const float*)d_in[3];
  const float* Wd = (const float*)d_in[4];
  const float* bd = (const float*)d_in[5];
  float* out = (float*)d_out;
  (void)in_sizes; (void)n_in; (void)out_size;
  if (ws_size < WS_NEED) return;
  const bool big = ws_size >= WS_BIG;

  char* ws  = (char*)d_ws;
  bf16* Ut  = (bf16*)(ws + OFF_UT);
  bf16* Uta = (bf16*)(ws + OFF_UTA);
  bf16* Wt  = (bf16*)(ws + OFF_WT);
  float* b2 = (float*)(ws + OFF_B2);
  bf16* Wdt = (bf16*)(ws + OFF_WDT);
  bf16* h0  = (bf16*)(ws + OFF_H0);
  bf16* h1  = (bf16*)(ws + OFF_H1);
  float* c  = (float*)(ws + OFF_C);
  bf16* hall= (bf16*)(ws + OFF_HALL);

  hipMemsetAsync(h0, 0, (size_t)NB*UNITS*2, stream);
  hipMemsetAsync(c,  0, (size_t)NB*UNITS*4, stream);
  prep_u_kernel<<<dim3(32, 8), 256, 0, stream>>>(U, W, Wd, Ut, Uta);
  prep_w_kernel<<<8, 256, 0, stream>>>(W, b, bd, Wd, Wt, b2, Wdt);

  if (big){
    // warmup: ping-pong, last step lands in hall[0]
    bf16* hcur = h0; bf16* hnxt = h1;
    for (int t = 0; t < TSEQ; ++t){
      bf16* dst = (t == TSEQ-1) ? hall : hnxt;
      lstm_step_kernel<1><<<512, 256, 0, stream>>>(hcur, dst, c, Ut, b, x + t*FEAT, Wt);
      hnxt = hcur; hcur = dst;
    }
    // AR: hall[s-1] -> hall[s]
    for (int s = 1; s < OUTS; ++s)
      lstm_step_kernel<0><<<512, 256, 0, stream>>>(hall + (size_t)(s-1)*HALL_SL,
                                                   hall + (size_t)s*HALL_SL,
                                                   c, Uta, b2, nullptr, nullptr);
    pred_all_kernel<<<dim3(NB/64, OUTS), 256, 0, stream>>>(hall, HALL_SL, 0, Wdt, bd, out);
  } else {
    bf16* hcur = h0; bf16* hnxt = h1;
    for (int t = 0; t < TSEQ; ++t){
      lstm_step_kernel<1><<<512, 256, 0, stream>>>(hcur, hnxt, c, Ut, b, x + t*FEAT, Wt);
      bf16* tmp = hcur; hcur = hnxt; hnxt = tmp;
    }
    pred_all_kernel<<<dim3(NB/64, 1), 256, 0, stream>>>(hcur, 0, 0, Wdt, bd, out);
    for (int s = 1; s < OUTS; ++s){
      lstm_step_kernel<0><<<512, 256, 0, stream>>>(hcur, hnxt, c, Uta, b2, nullptr, nullptr);
      bf16* tmp = hcur; hcur = hnxt; hnxt = tmp;
      pred_all_kernel<<<dim3(NB/64, 1), 256, 0, stream>>>(hcur, 0, s, Wdt, bd, out);
    }
  }
}